// Round 6
// baseline (499.578 us; speedup 1.0000x reference)
//
#include <hip/hip_runtime.h>
#include <math.h>

#define HDIM 2048   // hidden size H (== D_IN)
#define DOUT 1024
#define NLAYER 4
#define NBLK 1024   // fused kernel grid: 4 blocks/CU
#define TPB 256     // 4 waves: wave = gate

__device__ __forceinline__ float sigmoidf_(float x) {
    return 1.0f / (1.0f + expf(-x));
}

#define DOT4(acc, a, b) \
    acc = fmaf((a).x, (b).x, fmaf((a).y, (b).y, fmaf((a).z, (b).z, fmaf((a).w, (b).w, acc))))

// Zero the per-layer completion counters each call (ws poisoned / stale).
__global__ void init_cnt_k(unsigned* __restrict__ c) { c[threadIdx.x] = 0u; }

// ---------------- Fused pipelined persistent kernel ----------------
// 1024 blocks x 256 threads. Block b owns h-cells {2b,2b+1}; wave w = gate w.
// Key idea: each wave issues its ENTIRE per-layer weight-load share (16 x
// dwordx4 into registers) BEFORE any sync wait, so the flag wait hides under
// the HBM stream. Sync: producers atomicAdd cnt[l] (release, after agent-scope
// h stores); wave0 polls the single counter word; waves 1-3 spin on an LDS
// flag (no vmem). h is read with agent-scope relaxed atomic loads (cache-
// bypassing -> fresh across XCDs and graph replays, and NO acquire fence ->
// no vmcnt(0) drain of the in-flight weight stream).
__launch_bounds__(TPB, 4)
__global__ void lstm_fused_k(const float* __restrict__ x,
                             const float* __restrict__ h0,
                             const float* __restrict__ c0,
                             const float* __restrict__ Wih,
                             const float* __restrict__ Whh,
                             const float* __restrict__ bih,
                             const float* __restrict__ bhh,
                             const float* __restrict__ fcw,
                             const float* __restrict__ fcb,
                             float* __restrict__ out,
                             float* __restrict__ hbuf,   // [NLAYER*HDIM]
                             unsigned* __restrict__ cnt) // [64], [l] = #blocks done
{
    __shared__ unsigned ldsflag;   // highest globally-ready layer count
    __shared__ float    sg[2][8];  // double-buffered gate values
    __shared__ float    part[4];

    const int tid   = threadIdx.x;
    const int lane  = tid & 63;
    const int wave  = tid >> 6;    // gate index (i,f,g,o)
    const int blk   = blockIdx.x;
    const int cell0 = blk * 2;

    if (tid == 0) ldsflag = 0u;
    __syncthreads();

    for (int l = 0; l < NLAYER; ++l) {
        const float* Wi   = Wih + (size_t)l * 4 * HDIM * HDIM;
        const float* Wh   = Whh + (size_t)l * 4 * HDIM * HDIM;
        const int    row0 = wave * HDIM + cell0;
        const float4* r0 = (const float4*)(Wi + (size_t)row0 * HDIM);
        const float4* r1 = (const float4*)(Wi + (size_t)(row0 + 1) * HDIM);

        // ---- 1) issue full weight share for this layer (queues the HBM work)
        float4 w0[8], w1[8];
#pragma unroll
        for (int it = 0; it < 8; ++it) {
            w0[it] = r0[it * 64 + lane];
            w1[it] = r1[it * 64 + lane];
        }
        asm volatile("" ::: "memory");  // keep loads above the spin

        // ---- 2) wait for h_{l-1} (hidden under the in-flight weight stream)
        if (l > 0) {
            if (wave == 0) {
                while (__hip_atomic_load(&cnt[l - 1], __ATOMIC_RELAXED,
                                         __HIP_MEMORY_SCOPE_AGENT) < (unsigned)NBLK)
                    __builtin_amdgcn_s_sleep(16);
                __hip_atomic_store(&ldsflag, (unsigned)l, __ATOMIC_RELEASE,
                                   __HIP_MEMORY_SCOPE_WORKGROUP);
            } else {
                while (__hip_atomic_load(&ldsflag, __ATOMIC_ACQUIRE,
                                         __HIP_MEMORY_SCOPE_WORKGROUP) < (unsigned)l)
                    __builtin_amdgcn_s_sleep(1);
            }
        }
        asm volatile("" ::: "memory");

        // ---- 3) load h input (x: plain; hbuf: agent atomics, cache-bypassing)
        float4 hv[8];
        if (l == 0) {
#pragma unroll
            for (int it = 0; it < 8; ++it) hv[it] = ((const float4*)x)[it * 64 + lane];
        } else {
            float* hb = hbuf + (size_t)(l - 1) * HDIM;
#pragma unroll
            for (int it = 0; it < 8; ++it) {
                const int fi = 4 * (it * 64 + lane);
                hv[it].x = __hip_atomic_load(&hb[fi + 0], __ATOMIC_RELAXED, __HIP_MEMORY_SCOPE_AGENT);
                hv[it].y = __hip_atomic_load(&hb[fi + 1], __ATOMIC_RELAXED, __HIP_MEMORY_SCOPE_AGENT);
                hv[it].z = __hip_atomic_load(&hb[fi + 2], __ATOMIC_RELAXED, __HIP_MEMORY_SCOPE_AGENT);
                hv[it].w = __hip_atomic_load(&hb[fi + 3], __ATOMIC_RELAXED, __HIP_MEMORY_SCOPE_AGENT);
            }
        }

        // ---- 4) FMA sweep (+ exact per-chunk W_hh skip: zero h_prev chunks
        //          contribute exactly 0, so skipping their loads is lossless)
        const float4* hp4 = (const float4*)(h0 + l * HDIM);
        const float4* q0r = (const float4*)(Wh + (size_t)row0 * HDIM);
        const float4* q1r = (const float4*)(Wh + (size_t)(row0 + 1) * HDIM);
        float acc0 = 0.0f, acc1 = 0.0f;
#pragma unroll
        for (int it = 0; it < 8; ++it) {
            DOT4(acc0, w0[it], hv[it]);
            DOT4(acc1, w1[it], hv[it]);
            const float4 p = hp4[it * 64 + lane];
            if (p.x != 0.0f || p.y != 0.0f || p.z != 0.0f || p.w != 0.0f) {
                const float4 q0 = q0r[it * 64 + lane];
                const float4 q1 = q1r[it * 64 + lane];
                DOT4(acc0, q0, p);
                DOT4(acc1, q1, p);
            }
        }

        // ---- 5) gate combine
#pragma unroll
        for (int off = 32; off > 0; off >>= 1) {
            acc0 += __shfl_down(acc0, off, 64);
            acc1 += __shfl_down(acc1, off, 64);
        }
        if (lane == 0) {
            const float* bi = bih + (size_t)l * 4 * HDIM;
            const float* bh = bhh + (size_t)l * 4 * HDIM;
            sg[l & 1][wave * 2 + 0] = acc0 + bi[row0] + bh[row0];
            sg[l & 1][wave * 2 + 1] = acc1 + bi[row0 + 1] + bh[row0 + 1];
        }
        __syncthreads();  // only barrier per layer (streams already consumed)

        // ---- 6) elementwise cell update + publish (wave0 lanes 0-1)
        if (tid < 2) {
            const float iv = sg[l & 1][0 + tid];
            const float fv = sg[l & 1][2 + tid];
            const float gv = sg[l & 1][4 + tid];
            const float ov = sg[l & 1][6 + tid];
            const float cpv = c0[l * HDIM + cell0 + tid];
            const float cv = sigmoidf_(fv) * cpv + sigmoidf_(iv) * tanhf(gv);
            const float hvv = sigmoidf_(ov) * tanhf(cv);
            __hip_atomic_store(&hbuf[(size_t)l * HDIM + cell0 + tid], hvv,
                               __ATOMIC_RELAXED, __HIP_MEMORY_SCOPE_AGENT);
        }
        if (tid == 0)
            __hip_atomic_fetch_add(&cnt[l], 1u, __ATOMIC_RELEASE,
                                   __HIP_MEMORY_SCOPE_AGENT);
        // no second barrier: sg is double-buffered; next write to sg[l&1] is
        // two layers away and fenced by the next layer's __syncthreads chain.
    }

    // ---- FC epilogue: out[blk] = fcw[blk,:] @ h3 + fcb[blk]
    {
        const float4* fr = (const float4*)(fcw + (size_t)blk * HDIM);
        float4 fw0 = fr[wave * 128 + lane];
        float4 fw1 = fr[wave * 128 + 64 + lane];
        asm volatile("" ::: "memory");

        if (wave == 0) {
            while (__hip_atomic_load(&cnt[NLAYER - 1], __ATOMIC_RELAXED,
                                     __HIP_MEMORY_SCOPE_AGENT) < (unsigned)NBLK)
                __builtin_amdgcn_s_sleep(16);
            __hip_atomic_store(&ldsflag, (unsigned)NLAYER, __ATOMIC_RELEASE,
                               __HIP_MEMORY_SCOPE_WORKGROUP);
        } else {
            while (__hip_atomic_load(&ldsflag, __ATOMIC_ACQUIRE,
                                     __HIP_MEMORY_SCOPE_WORKGROUP) < (unsigned)NLAYER)
                __builtin_amdgcn_s_sleep(1);
        }
        asm volatile("" ::: "memory");

        float* h3 = hbuf + (size_t)(NLAYER - 1) * HDIM;
        float4 ha, hb2;
        {
            const int fa = 4 * (wave * 128 + lane);
            const int fb = fa + 256;
            ha.x  = __hip_atomic_load(&h3[fa + 0], __ATOMIC_RELAXED, __HIP_MEMORY_SCOPE_AGENT);
            ha.y  = __hip_atomic_load(&h3[fa + 1], __ATOMIC_RELAXED, __HIP_MEMORY_SCOPE_AGENT);
            ha.z  = __hip_atomic_load(&h3[fa + 2], __ATOMIC_RELAXED, __HIP_MEMORY_SCOPE_AGENT);
            ha.w  = __hip_atomic_load(&h3[fa + 3], __ATOMIC_RELAXED, __HIP_MEMORY_SCOPE_AGENT);
            hb2.x = __hip_atomic_load(&h3[fb + 0], __ATOMIC_RELAXED, __HIP_MEMORY_SCOPE_AGENT);
            hb2.y = __hip_atomic_load(&h3[fb + 1], __ATOMIC_RELAXED, __HIP_MEMORY_SCOPE_AGENT);
            hb2.z = __hip_atomic_load(&h3[fb + 2], __ATOMIC_RELAXED, __HIP_MEMORY_SCOPE_AGENT);
            hb2.w = __hip_atomic_load(&h3[fb + 3], __ATOMIC_RELAXED, __HIP_MEMORY_SCOPE_AGENT);
        }
        float acc = 0.0f;
        DOT4(acc, fw0, ha);
        DOT4(acc, fw1, hb2);
#pragma unroll
        for (int off = 32; off > 0; off >>= 1) acc += __shfl_down(acc, off, 64);
        if (lane == 0) part[wave] = acc;
        __syncthreads();
        if (tid == 0)
            out[blk] = part[0] + part[1] + part[2] + part[3] + fcb[blk];
    }
}

// ---------------- Fallback path (proven 58 us, R1) ----------------
__launch_bounds__(256)
__global__ void lstm_layer_k(const float* __restrict__ Wi,
                             const float* __restrict__ Wh,
                             const float* __restrict__ bi,
                             const float* __restrict__ bh,
                             const float* __restrict__ hin,
                             const float* __restrict__ hprev,
                             const float* __restrict__ cprev,
                             float* __restrict__ hout)
{
    __shared__ float4 sh_in[HDIM / 4];
    __shared__ float  sgates[8];
    __shared__ int    nzflag;

    const int tid = threadIdx.x;
    if (tid == 0) nzflag = 0;
    __syncthreads();

    int nz = 0;
#pragma unroll
    for (int i = 0; i < 2; ++i) {
        const int idx = tid + i * 256;
        sh_in[idx] = ((const float4*)hin)[idx];
        float4 p = ((const float4*)hprev)[idx];
        if (p.x != 0.0f || p.y != 0.0f || p.z != 0.0f || p.w != 0.0f) nz = 1;
    }
    if (nz) nzflag = 1;
    __syncthreads();
    const int any_prev = nzflag;

    const int lane = tid & 63;
    const int wave = tid >> 6;
    const int cell0 = blockIdx.x * 2;
    const int row0 = wave * HDIM + cell0;

    const float4* r0 = (const float4*)(Wi + (size_t)row0 * HDIM);
    const float4* r1 = (const float4*)(Wi + (size_t)(row0 + 1) * HDIM);

    float acc0 = 0.0f, acc1 = 0.0f;
#pragma unroll
    for (int it = 0; it < 8; ++it) {
        const int idx = it * 64 + lane;
        const float4 a0 = r0[idx];
        const float4 a1 = r1[idx];
        const float4 hv = sh_in[idx];
        DOT4(acc0, a0, hv);
        DOT4(acc1, a1, hv);
    }

    if (any_prev) {
        const float4* q0 = (const float4*)(Wh + (size_t)row0 * HDIM);
        const float4* q1 = (const float4*)(Wh + (size_t)(row0 + 1) * HDIM);
        const float4* pv4 = (const float4*)hprev;
#pragma unroll
        for (int it = 0; it < 8; ++it) {
            const int idx = it * 64 + lane;
            const float4 a0 = q0[idx];
            const float4 a1 = q1[idx];
            const float4 pv = pv4[idx];
            DOT4(acc0, a0, pv);
            DOT4(acc1, a1, pv);
        }
    }

#pragma unroll
    for (int off = 32; off > 0; off >>= 1) {
        acc0 += __shfl_down(acc0, off, 64);
        acc1 += __shfl_down(acc1, off, 64);
    }
    if (lane == 0) {
        sgates[wave * 2 + 0] = acc0 + bi[row0] + bh[row0];
        sgates[wave * 2 + 1] = acc1 + bi[row0 + 1] + bh[row0 + 1];
    }
    __syncthreads();

    if (tid < 2) {
        const float iv = sgates[0 * 2 + tid];
        const float fv = sgates[1 * 2 + tid];
        const float gv = sgates[2 * 2 + tid];
        const float ov = sgates[3 * 2 + tid];
        const float cp = cprev[cell0 + tid];
        const float cv = sigmoidf_(fv) * cp + sigmoidf_(iv) * tanhf(gv);
        hout[cell0 + tid] = sigmoidf_(ov) * tanhf(cv);
    }
}

__launch_bounds__(256)
__global__ void fc_k(const float* __restrict__ W, const float* __restrict__ b,
                     const float* __restrict__ h, float* __restrict__ out)
{
    __shared__ float4 sh[HDIM / 4];
    const int tid = threadIdx.x;
#pragma unroll
    for (int i = 0; i < 2; ++i)
        sh[tid + i * 256] = ((const float4*)h)[tid + i * 256];
    __syncthreads();

    const int lane = tid & 63;
    const int wave = tid >> 6;
    const int row = blockIdx.x * 4 + wave;

    const float4* r = (const float4*)(W + (size_t)row * HDIM);
    float acc = 0.0f;
#pragma unroll
    for (int it = 0; it < 8; ++it) {
        const int idx = it * 64 + lane;
        const float4 a = r[idx];
        const float4 hv = sh[idx];
        DOT4(acc, a, hv);
    }
#pragma unroll
    for (int off = 32; off > 0; off >>= 1) acc += __shfl_down(acc, off, 64);
    if (lane == 0) out[row] = acc + b[row];
}

extern "C" void kernel_launch(void* const* d_in, const int* in_sizes, int n_in,
                              void* d_out, int out_size, void* d_ws, size_t ws_size,
                              hipStream_t stream) {
    const float* x   = (const float*)d_in[0];
    const float* h0  = (const float*)d_in[1];
    const float* c0  = (const float*)d_in[2];
    const float* Wih = (const float*)d_in[3];
    const float* Whh = (const float*)d_in[4];
    const float* bih = (const float*)d_in[5];
    const float* bhh = (const float*)d_in[6];
    const float* fcw = (const float*)d_in[7];
    const float* fcb = (const float*)d_in[8];
    float* out = (float*)d_out;

    float*    hbuf = (float*)d_ws;                          // 32 KiB
    unsigned* cnt  = (unsigned*)((char*)d_ws + 32 * 1024);  // 64 u32

    init_cnt_k<<<1, 64, 0, stream>>>(cnt);

    void* args[] = {(void*)&x, (void*)&h0, (void*)&c0, (void*)&Wih, (void*)&Whh,
                    (void*)&bih, (void*)&bhh, (void*)&fcw, (void*)&fcb,
                    (void*)&out, (void*)&hbuf, (void*)&cnt};
    hipError_t e = hipLaunchCooperativeKernel((void*)lstm_fused_k,
                                              dim3(NBLK), dim3(TPB),
                                              args, 0, stream);
    if (e != hipSuccess) {
        // Fallback: 5 sequential launches (identical math -> identical output).
        const size_t wstride = (size_t)4 * HDIM * HDIM;
        const int    bstride = 4 * HDIM;
        float* hb0 = hbuf;
        float* hb1 = hbuf + HDIM;
        const float* hin = x;
        float* houts[4] = {hb0, hb1, hb0, hb1};
        for (int l = 0; l < 4; ++l) {
            lstm_layer_k<<<HDIM / 2, 256, 0, stream>>>(
                Wih + (size_t)l * wstride, Whh + (size_t)l * wstride,
                bih + l * bstride, bhh + l * bstride,
                hin, h0 + l * HDIM, c0 + l * HDIM, houts[l]);
            hin = houts[l];
        }
        fc_k<<<DOUT / 4, 256, 0, stream>>>(fcw, fcb, hb1, out);
    }
}